// Round 4
// baseline (366.213 us; speedup 1.0000x reference)
//
#include <hip/hip_runtime.h>

// Local variance over a 5x5 sliding window, reflect padding.
// Pure-register separable stencil: NO LDS, NO barriers.
//
// Thread tile: 8 (W) x 16 (H) outputs. Block: 32 col-threads x 8 row-threads.
// Block tile: 256 (W) x 128 (H). Grid: (1024/256, 1024/128, 48) = (4,8,48).
//
// Per input row (20 rows = 16 + 4 halo) each thread loads EXACTLY the 12
// columns it needs: float2 @ c0-2 | float4 @ c0 | float4 @ c0+4 | float2 @ c0+8
// (all naturally aligned since c0 % 8 == 0). Horizontal 5-sums of x and x^2
// via sliding adds; vertical 5-window via a 5-deep register ring buffer
// (fully unrolled -> pure registers). Output stores are nontemporal (never
// re-read; preserve L2/L3 for input halo reuse).
//
// Reflect (jnp "reflect", no edge repeat): rows are wave-uniform index math.
// Columns: only the outermost thread columns need fixes:
//   left  (c0==0):     x[-2]->x[2]=A.z, x[-1]->x[1]=A.y  (clamp L addr to c0)
//   right (c0==W-8):   x[W]->x[W-2]=B.z, x[W+1]->x[W-3]=B.y (clamp R addr)

constexpr int NT = 256;
typedef float v4f __attribute__((ext_vector_type(4)));

__global__ __launch_bounds__(NT, 3)
void lvar5x5_reg8_kernel(const float* __restrict__ in, float* __restrict__ out,
                         int H, int W) {
    const int tx = threadIdx.x & 31;          // column group within block
    const int ty = threadIdx.x >> 5;          // thread-row (0..7)
    const int c0 = blockIdx.x * 256 + tx * 8; // first output col (c0 % 8 == 0)
    const int r0 = blockIdx.y * 128 + ty * 16;// first output row
    const size_t plane = (size_t)H * W;
    const float* __restrict__ img = in + (size_t)blockIdx.z * plane;
    float* __restrict__ o = out + (size_t)blockIdx.z * plane;

    const bool cL = (c0 == 0);
    const bool cR = (c0 == W - 8);
    const int aL = cL ? c0 : c0 - 2;          // 8B-aligned halo load col
    const int aR = cR ? c0 + 4 : c0 + 8;      // in-bounds halo load col

    float rh[5][8];                           // ring: horizontal sums of x
    float rq[5][8];                           // ring: horizontal sums of x^2
    float sh[8], sq[8];                       // vertical running sums
#pragma unroll
    for (int j = 0; j < 8; ++j) { sh[j] = 0.f; sq[j] = 0.f; }

    const float inv = 1.0f / 25.0f;

#pragma unroll
    for (int i = 0; i < 20; ++i) {
        int gy = r0 - 2 + i;
        gy = (gy < 0) ? -gy : ((gy >= H) ? (2 * H - 2 - gy) : gy);
        const float* __restrict__ row = img + (size_t)gy * W;

        const float2 L = *reinterpret_cast<const float2*>(row + aL);
        const float4 A = *reinterpret_cast<const float4*>(row + c0);
        const float4 B = *reinterpret_cast<const float4*>(row + c0 + 4);
        const float2 R = *reinterpret_cast<const float2*>(row + aR);

        float xv[12];
        xv[0] = L.x; xv[1] = L.y;
        xv[2] = A.x; xv[3] = A.y; xv[4] = A.z; xv[5] = A.w;
        xv[6] = B.x; xv[7] = B.y; xv[8] = B.z; xv[9] = B.w;
        xv[10] = R.x; xv[11] = R.y;
        if (cL) { xv[0] = A.z; xv[1] = A.y; }   // reflect cols -2,-1 -> 2,1
        if (cR) { xv[10] = B.z; xv[11] = B.y; } // reflect cols W,W+1 -> W-2,W-3

        float yv[12];
#pragma unroll
        for (int k = 0; k < 12; ++k) yv[k] = xv[k] * xv[k];

        // horizontal sliding 5-sums (output j uses xv[j..j+4])
        float h[8], q[8];
        h[0] = xv[0] + xv[1] + xv[2] + xv[3] + xv[4];
        q[0] = yv[0] + yv[1] + yv[2] + yv[3] + yv[4];
#pragma unroll
        for (int j = 1; j < 8; ++j) {
            h[j] = h[j - 1] - xv[j - 1] + xv[j + 4];
            q[j] = q[j - 1] - yv[j - 1] + yv[j + 4];
        }

        const int s = i % 5;                  // constant after unroll
#pragma unroll
        for (int j = 0; j < 8; ++j) {
            if (i >= 5) { sh[j] -= rh[s][j]; sq[j] -= rq[s][j]; }
            rh[s][j] = h[j]; rq[s][j] = q[j];
            sh[j] += h[j];   sq[j] += q[j];
        }

        if (i >= 4) {
            float res[8];
#pragma unroll
            for (int j = 0; j < 8; ++j) {
                const float m = sh[j] * inv;
                res[j] = fmaf(-m, m, sq[j] * inv);
            }
            float* dst = o + (size_t)(r0 + i - 4) * W + c0;
            v4f lo = { res[0], res[1], res[2], res[3] };
            v4f hi = { res[4], res[5], res[6], res[7] };
            __builtin_nontemporal_store(lo, (v4f*)dst);
            __builtin_nontemporal_store(hi, (v4f*)(dst + 4));
        }
    }
}

extern "C" void kernel_launch(void* const* d_in, const int* in_sizes, int n_in,
                              void* d_out, int out_size, void* d_ws, size_t ws_size,
                              hipStream_t stream) {
    const float* image = (const float*)d_in[0];
    float* out = (float*)d_out;

    const int H = 1024, W = 1024;
    const int BC = out_size / (H * W);        // 48

    dim3 grid(W / 256, H / 128, BC);          // (4, 8, 48) = 1536 blocks
    dim3 block(NT);
    lvar5x5_reg8_kernel<<<grid, block, 0, stream>>>(image, out, H, W);
}